// Round 8
// baseline (2802.766 us; speedup 1.0000x reference)
//
#include <hip/hip_runtime.h>
#include <hip/hip_fp16.h>
#include <cstddef>

#define NN 100000
#define EE 3200000
#define EPSB 1e-5f
#define NB 391      // buckets = ceil(NN/256)
#define BCAP 10240  // per-bucket edge capacity
#define NSLOT 16    // replicated BN accumulator slots (stride 1024 floats)

typedef _Float16 half8 __attribute__((ext_vector_type(8)));
typedef float floatx4 __attribute__((ext_vector_type(4)));

// ---------------------------------------------------------------- CSR build
// packed record: src (17 bits) | dst&255 (8 bits) << 17

__global__ __launch_bounds__(256) void k_bscat(const int* __restrict__ src,
                                               const int* __restrict__ dst,
                                               int* __restrict__ bcur,
                                               unsigned* __restrict__ barr) {
    __shared__ int hist[NB];
    __shared__ int base[NB];
    int tid = threadIdx.x;
    for (int b = tid; b < NB; b += 256) hist[b] = 0;
    __syncthreads();
    int e0 = blockIdx.x * 4096;
    int d[16], s[16];
    #pragma unroll
    for (int j = 0; j < 16; j++) {
        int e = e0 + j * 256 + tid;
        if (e < EE) {
            d[j] = dst[e];
            s[j] = src[e];
            atomicAdd(&hist[d[j] >> 8], 1);
        } else d[j] = -1;
    }
    __syncthreads();
    for (int b = tid; b < NB; b += 256) {
        int c = hist[b];
        base[b] = (c > 0) ? atomicAdd(&bcur[b], c) : 0;
        hist[b] = 0;
    }
    __syncthreads();
    #pragma unroll
    for (int j = 0; j < 16; j++) {
        if (d[j] >= 0) {
            int b = d[j] >> 8;
            int r = atomicAdd(&hist[b], 1);
            barr[(size_t)b * BCAP + base[b] + r] =
                (unsigned)s[j] | ((unsigned)(d[j] & 255) << 17);
        }
    }
}

__global__ __launch_bounds__(1024) void k_bdeg(const int* __restrict__ bcur,
                                               const unsigned* __restrict__ barr,
                                               int* __restrict__ degcnt) {
    __shared__ int h[256];
    int b = blockIdx.x;
    if (threadIdx.x < 256) h[threadIdx.x] = 0;
    __syncthreads();
    int cnt = bcur[b];
    const unsigned* p = barr + (size_t)b * BCAP;
    for (int t = threadIdx.x; t < cnt; t += 1024)
        atomicAdd(&h[(p[t] >> 17) & 255], 1);
    __syncthreads();
    if (threadIdx.x < 256) {
        int node = (b << 8) + threadIdx.x;
        if (node < NN) degcnt[node] = h[threadIdx.x];
    }
}

__global__ __launch_bounds__(1024) void k_place(const int* __restrict__ bcur,
                                                const unsigned* __restrict__ barr,
                                                const int* __restrict__ rowptr,
                                                int* __restrict__ col) {
    __shared__ int cur[256];
    int b = blockIdx.x;
    if (threadIdx.x < 256) {
        int node = (b << 8) + threadIdx.x;
        cur[threadIdx.x] = (node < NN) ? rowptr[node] : 0;
    }
    __syncthreads();
    int cnt = bcur[b];
    const unsigned* p = barr + (size_t)b * BCAP;
    for (int t = threadIdx.x; t < cnt; t += 1024) {
        unsigned e = p[t];
        int pos = atomicAdd(&cur[(e >> 17) & 255], 1);
        col[pos] = (int)(e & 0x1FFFFu);
    }
}

__global__ void k_deg(const int* __restrict__ degcnt, float* __restrict__ dis) {
    int i = blockIdx.x * blockDim.x + threadIdx.x;
    if (i < NN) {
        float d = (float)degcnt[i] + 1.0f;
        dis[i] = rsqrtf(d);
    }
}

__global__ void k_scan_block(const int* __restrict__ in, int* __restrict__ out,
                             int* __restrict__ blksum, int n) {
    __shared__ int s[1024];
    int i = blockIdx.x * 1024 + threadIdx.x;
    int v = (i < n) ? in[i] : 0;
    s[threadIdx.x] = v;
    __syncthreads();
    for (int off = 1; off < 1024; off <<= 1) {
        int t = (threadIdx.x >= off) ? s[threadIdx.x - off] : 0;
        __syncthreads();
        s[threadIdx.x] += t;
        __syncthreads();
    }
    if (i < n) out[i] = s[threadIdx.x] - v;  // exclusive
    if (threadIdx.x == 1023) blksum[blockIdx.x] = s[1023];
}

__global__ void k_scan_top(int* __restrict__ blksum, int nb) {
    if (threadIdx.x == 0) {
        int acc = 0;
        for (int b = 0; b < nb; b++) { int v = blksum[b]; blksum[b] = acc; acc += v; }
    }
}

__global__ void k_scan_add(int* __restrict__ out, const int* __restrict__ blksum, int n) {
    int i = blockIdx.x * 1024 + threadIdx.x;
    if (i < n) out[i] += blksum[blockIdx.x];
}

// ---------------------------------------------------------------- casts / packing

__global__ void k_f2h(const float4* __restrict__ in, uint2* __restrict__ out, int n4) {
    int t = blockIdx.x * blockDim.x + threadIdx.x;
    if (t >= n4) return;
    float4 v = in[t];
    union { __half2 h; unsigned u; } a, b;
    a.h = __floats2half2_rn(v.x, v.y);
    b.h = __floats2half2_rn(v.z, v.w);
    out[t] = make_uint2(a.u, b.u);
}

__global__ void k_wpack(const float* __restrict__ W, __half* __restrict__ Wp,
                        int K, int N) {
    int t = blockIdx.x * blockDim.x + threadIdx.x;
    if (t < K * N) {
        int k = t / N, n = t - k * N;
        Wp[(size_t)n * K + k] = __float2half(W[t]);
    }
}

// ---------------------------------------------------------------- MFMA GEMM
// OUT16: C fp16 = dis[row]*acc. else: C fp32 = acc+bias, + fused BN-stat slots.

template<int NT, bool OUT16, bool FUSEBN>
__global__ __launch_bounds__(256) void k_mgemm(const __half* __restrict__ A,
                                               const __half* __restrict__ Wp,
                                               void* __restrict__ Cv,
                                               int M, int K, int N,
                                               const float* __restrict__ dis,
                                               const float* __restrict__ bias,
                                               float* __restrict__ bnslots) {
    constexpr int TN = NT * 16;
    __shared__ __half Ash[128][40];
    __shared__ __half Bsh[TN][40];
    int tid  = threadIdx.x;
    int wave = tid >> 6;
    int lane = tid & 63;
    int quad = lane >> 4;
    int l16  = lane & 15;
    int bm = blockIdx.x * 128;
    int bn = blockIdx.y * TN;

    floatx4 acc[2][NT];
    #pragma unroll
    for (int mt = 0; mt < 2; mt++)
        #pragma unroll
        for (int nt = 0; nt < NT; nt++)
            acc[mt][nt] = (floatx4){0.f, 0.f, 0.f, 0.f};

    for (int k0 = 0; k0 < K; k0 += 32) {
        #pragma unroll
        for (int it = 0; it < 2; it++) {
            int u = tid + it * 256;
            int row = u >> 2, seg = u & 3;
            int grow = bm + row;
            uint4 v = make_uint4(0, 0, 0, 0);
            if (grow < M) v = *(const uint4*)&A[(size_t)grow * K + k0 + seg * 8];
            *(uint4*)&Ash[row][seg * 8] = v;
        }
        if (tid < TN * 4) {
            int n = tid >> 2, seg = tid & 3;
            uint4 v = *(const uint4*)&Wp[(size_t)(bn + n) * K + k0 + seg * 8];
            *(uint4*)&Bsh[n][seg * 8] = v;
        }
        __syncthreads();
        half8 a[2], b[NT];
        #pragma unroll
        for (int mt = 0; mt < 2; mt++)
            a[mt] = *(const half8*)&Ash[wave * 32 + mt * 16 + l16][quad * 8];
        #pragma unroll
        for (int nt = 0; nt < NT; nt++)
            b[nt] = *(const half8*)&Bsh[nt * 16 + l16][quad * 8];
        #pragma unroll
        for (int mt = 0; mt < 2; mt++)
            #pragma unroll
            for (int nt = 0; nt < NT; nt++)
                acc[mt][nt] = __builtin_amdgcn_mfma_f32_16x16x32_f16(
                    a[mt], b[nt], acc[mt][nt], 0, 0, 0);
        __syncthreads();
    }

    float bsum[NT] = {}, bsq[NT] = {};
    #pragma unroll
    for (int mt = 0; mt < 2; mt++) {
        #pragma unroll
        for (int r = 0; r < 4; r++) {
            int grow = bm + wave * 32 + mt * 16 + quad * 4 + r;
            if (grow >= M) continue;
            if (OUT16) {
                float ds = dis[grow];
                __half* C = (__half*)Cv;
                #pragma unroll
                for (int nt = 0; nt < NT; nt++) {
                    int gcol = bn + nt * 16 + l16;
                    C[(size_t)grow * N + gcol] = __float2half(ds * acc[mt][nt][r]);
                }
            } else {
                float* C = (float*)Cv;
                #pragma unroll
                for (int nt = 0; nt < NT; nt++) {
                    int gcol = bn + nt * 16 + l16;
                    float val = acc[mt][nt][r] + bias[gcol];
                    C[(size_t)grow * N + gcol] = val;
                    if (FUSEBN) { bsum[nt] += val; bsq[nt] += val * val; }
                }
            }
        }
    }
    if (FUSEBN) {
        int slot = (blockIdx.x + blockIdx.y) & (NSLOT - 1);
        #pragma unroll
        for (int nt = 0; nt < NT; nt++) {
            float v = bsum[nt], w = bsq[nt];
            v += __shfl_xor(v, 16); w += __shfl_xor(w, 16);
            v += __shfl_xor(v, 32); w += __shfl_xor(w, 32);
            if ((threadIdx.x & 63) < 16) {
                int gcol = bn + nt * 16 + l16;
                atomicAdd(&bnslots[slot * 1024 + gcol], v);
                atomicAdd(&bnslots[slot * 1024 + 512 + gcol], w);
            }
        }
    }
}

// layer-1 staging: Hh = fp16(dis[i] * act16[i][:]), d=128 (16 uint4/row)
__global__ void k_scale16(const uint4* __restrict__ X, const float* __restrict__ dis,
                          uint4* __restrict__ out) {
    int t = blockIdx.x * blockDim.x + threadIdx.x;
    if (t >= NN * 16) return;
    int row = t >> 4;
    float ds = dis[row];
    uint4 v = X[t];
    const __half2* hp = (const __half2*)&v;
    uint4 o;
    __half2* op = (__half2*)&o;
    #pragma unroll
    for (int k = 0; k < 4; k++) {
        float2 f = __half22float2(hp[k]);
        op[k] = __floats2half2_rn(ds * f.x, ds * f.y);
    }
    out[t] = o;
}

// ---------------------------------------------------------------- aggregation
// Full-row gather (16B/thread, TPN = d/8 threads/node). R7 lesson: never
// slice a row below L2-line granularity — 32B stripes caused 4x FETCH.

__device__ __forceinline__ void acc_row(float* acc, const uint4& r) {
    const __half2* hp = (const __half2*)&r;
    #pragma unroll
    for (int k = 0; k < 4; k++) {
        float2 f2 = __half22float2(hp[k]);
        acc[2 * k]     += f2.x;
        acc[2 * k + 1] += f2.y;
    }
}

// out fp32 = dis*(sum+self)+bias with optional fused BN; or fp16 (no bias/BN).
template<int TPN, bool OUT16, bool FUSEBN>
__global__ __launch_bounds__(256) void k_agg_h(const uint4* __restrict__ Hs,
                                               void* __restrict__ outv,
                                               const int* __restrict__ rowptr,
                                               const int* __restrict__ degcnt,
                                               const int* __restrict__ colv,
                                               const float* __restrict__ dis,
                                               const float* __restrict__ bias,
                                               float* __restrict__ bnslots) {
    constexpr int G = 256 / TPN;
    int g    = threadIdx.x / TPN;
    int lane = threadIdx.x % TPN;
    int i = blockIdx.x * G + g;
    bool valid = i < NN;
    float o[8] = {};
    if (valid) {
        int beg = rowptr[i];
        int cnt = degcnt[i];
        const uint4* base = Hs + lane;
        float acc[8] = {};
        int e = 0;
        for (; e + 8 <= cnt; e += 8) {
            int c[8];
            #pragma unroll
            for (int j = 0; j < 8; j++) c[j] = colv[beg + e + j];
            uint4 r[8];
            #pragma unroll
            for (int j = 0; j < 8; j++) r[j] = base[(size_t)c[j] * TPN];
            #pragma unroll
            for (int j = 0; j < 8; j++) acc_row(acc, r[j]);
        }
        for (; e < cnt; e++) {
            uint4 r = base[(size_t)colv[beg + e] * TPN];
            acc_row(acc, r);
        }
        uint4 rs = base[(size_t)i * TPN];  // self-loop
        acc_row(acc, rs);
        float ds = dis[i];
        #pragma unroll
        for (int k = 0; k < 8; k++) o[k] = ds * acc[k];
        if (OUT16) {
            uint4 ov;
            __half2* op = (__half2*)&ov;
            #pragma unroll
            for (int k = 0; k < 4; k++) op[k] = __floats2half2_rn(o[2 * k], o[2 * k + 1]);
            ((uint4*)outv)[(size_t)i * TPN + lane] = ov;
        } else {
            float4 b0 = ((const float4*)bias)[lane * 2];
            float4 b1 = ((const float4*)bias)[lane * 2 + 1];
            o[0] += b0.x; o[1] += b0.y; o[2] += b0.z; o[3] += b0.w;
            o[4] += b1.x; o[5] += b1.y; o[6] += b1.z; o[7] += b1.w;
            float4* out = (float4*)outv;
            size_t ob = (size_t)i * (2 * TPN) + lane * 2;
            out[ob]     = make_float4(o[0], o[1], o[2], o[3]);
            out[ob + 1] = make_float4(o[4], o[5], o[6], o[7]);
        }
    }
    if (FUSEBN) {  // wave reduce across nodes (invalid threads contribute 0)
        int slot = blockIdx.x & (NSLOT - 1);
        int wl = threadIdx.x & 63;
        #pragma unroll
        for (int k = 0; k < 8; k++) {
            float v = o[k], w = o[k] * o[k];
            #pragma unroll
            for (int off = TPN; off < 64; off <<= 1) {
                v += __shfl_xor(v, off);
                w += __shfl_xor(w, off);
            }
            if (wl < TPN) {
                int f = wl * 8 + k;
                atomicAdd(&bnslots[slot * 1024 + f], v);
                atomicAdd(&bnslots[slot * 1024 + 512 + f], w);
            }
        }
    }
}

// ---------------------------------------------------------------- BatchNorm

__global__ void k_bnfin(const float* __restrict__ slots, const float* __restrict__ g,
                        const float* __restrict__ be, float* __restrict__ AB, int d) {
    int f = threadIdx.x;
    if (f < d) {
        float sum = 0.f, sq = 0.f;
        #pragma unroll
        for (int sl = 0; sl < NSLOT; sl++) {
            sum += slots[sl * 1024 + f];
            sq  += slots[sl * 1024 + 512 + f];
        }
        float mu  = sum / (float)NN;
        float var = sq / (float)NN - mu * mu;
        var = fmaxf(var, 0.f);
        float inv = rsqrtf(var + EPSB);
        float a = g[f] * inv;
        AB[f]     = a;
        AB[d + f] = be[f] - mu * a;
    }
}

__global__ void k_norm16(const float4* __restrict__ X, const float* __restrict__ AB,
                         uint2* __restrict__ Y, int d, int total4) {
    int t = blockIdx.x * blockDim.x + threadIdx.x;
    if (t >= total4) return;
    int f0 = (t * 4) & (d - 1);
    float4 v = X[t];
    float a0 = AB[f0],     a1 = AB[f0 + 1], a2 = AB[f0 + 2], a3 = AB[f0 + 3];
    float c0 = AB[d + f0], c1 = AB[d + f0 + 1], c2 = AB[d + f0 + 2], c3 = AB[d + f0 + 3];
    float o0 = fmaxf(v.x * a0 + c0, 0.f);
    float o1 = fmaxf(v.y * a1 + c1, 0.f);
    float o2 = fmaxf(v.z * a2 + c2, 0.f);
    float o3 = fmaxf(v.w * a3 + c3, 0.f);
    union { __half2 h; unsigned u; } p, q;
    p.h = __floats2half2_rn(o0, o1);
    q.h = __floats2half2_rn(o2, o3);
    Y[t] = make_uint2(p.u, q.u);
}

// ---------------------------------------------------------------- final edge MLP

__global__ __launch_bounds__(256) void k_edge16(const uint4* __restrict__ X,
                                                const int* __restrict__ src,
                                                const int* __restrict__ dst,
                                                const float* __restrict__ fcw,
                                                const float* __restrict__ fcb,
                                                float* __restrict__ out) {
    int lane = threadIdx.x & 3;
    size_t t = (size_t)blockIdx.x * 256 + threadIdx.x;
    int eid = (int)(t >> 2);
    if (eid >= EE) return;
    int s = src[eid], d = dst[eid];
    uint4 av = X[(size_t)s * 4 + lane];
    uint4 bv = X[(size_t)d * 4 + lane];
    const __half2* ap = (const __half2*)&av;
    const __half2* bp2 = (const __half2*)&bv;
    float v = 0.f;
    #pragma unroll
    for (int k = 0; k < 4; k++) {
        float2 fa = __half22float2(ap[k]);
        float2 fb = __half22float2(bp2[k]);
        float w0 = fcw[lane * 8 + 2 * k];
        float w1 = fcw[lane * 8 + 2 * k + 1];
        v += fa.x * fb.x * w0 + fa.y * fb.y * w1;
    }
    v += __shfl_xor(v, 1, 4);
    v += __shfl_xor(v, 2, 4);
    if (lane == 0) out[eid] = 1.f / (1.f + expf(-(v + fcb[0])));
}

// ---------------------------------------------------------------- launch

extern "C" void kernel_launch(void* const* d_in, const int* in_sizes, int n_in,
                              void* d_out, int out_size, void* d_ws, size_t ws_size,
                              hipStream_t stream) {
    const float* x0 = (const float*)d_in[0];
    const int* ei   = (const int*)d_in[1];
    const int* srcv = ei;
    const int* dstv = ei + EE;
    const float *W[5], *bp[5], *gp[5], *bep[5];
    int idx = 2;
    for (int l = 0; l < 5; l++) {
        W[l]   = (const float*)d_in[idx++];
        bp[l]  = (const float*)d_in[idx++];
        gp[l]  = (const float*)d_in[idx++];
        bep[l] = (const float*)d_in[idx++];
    }
    const float* fcw = (const float*)d_in[22];
    const float* fcb = (const float*)d_in[23];

    char* ws = (char*)d_ws;
    size_t off = 0;
    auto alloc = [&](size_t bytes) -> void* {
        void* p = ws + off;
        off = (off + bytes + 255) & ~(size_t)255;
        return p;
    };
    float*    bufA    = (float*)   alloc((size_t)NN * 256 * 4);
    __half*   act16   = (__half*)  alloc((size_t)NN * 256 * 2);
    __half*   x16     = (__half*)  alloc((size_t)NN * 128 * 2);
    __half*   Hh      = (__half*)  alloc((size_t)NN * 128 * 2);
    unsigned* barr    = (unsigned*)alloc((size_t)NB * BCAP * 4);
    int*      colv    = (int*)     alloc((size_t)EE * 4);
    int*      rowptr  = (int*)     alloc((size_t)NN * 4);
    int*      degcnt  = (int*)     alloc((size_t)NN * 4);
    float*    dis     = (float*)   alloc((size_t)NN * 4);
    int*      bcur    = (int*)     alloc((size_t)NB * 4);
    int*      scnblk  = (int*)     alloc(4096);
    float*    bnslots = (float*)   alloc((size_t)NSLOT * 1024 * 4);  // 64KB
    float*    bnAB    = (float*)   alloc(512 * 4);
    __half* Wp[5];
    const int dims[6] = {128, 128, 256, 128, 64, 32};
    for (int l = 0; l < 5; l++) Wp[l] = (__half*)alloc((size_t)dims[l] * dims[l + 1] * 2);

    // ---- CSR build (binned counting sort)
    hipMemsetAsync(bcur, 0, (size_t)NB * 4, stream);
    k_bscat<<<(EE + 4095) / 4096, 256, 0, stream>>>(srcv, dstv, bcur, barr);
    k_bdeg<<<NB, 1024, 0, stream>>>(bcur, barr, degcnt);
    k_deg<<<(NN + 255) / 256, 256, 0, stream>>>(degcnt, dis);
    int nScanBlk = (NN + 1023) / 1024;
    k_scan_block<<<nScanBlk, 1024, 0, stream>>>(degcnt, rowptr, scnblk, NN);
    k_scan_top<<<1, 64, 0, stream>>>(scnblk, nScanBlk);
    k_scan_add<<<nScanBlk, 1024, 0, stream>>>(rowptr, scnblk, NN);
    k_place<<<NB, 1024, 0, stream>>>(bcur, barr, rowptr, colv);

    // ---- casts / weight packs
    k_f2h<<<(NN * 128 / 4 + 255) / 256, 256, 0, stream>>>(
        (const float4*)x0, (uint2*)x16, NN * 128 / 4);
    for (int l = 0; l < 5; l++) {
        int kn = dims[l] * dims[l + 1];
        k_wpack<<<(kn + 255) / 256, 256, 0, stream>>>(W[l], Wp[l], dims[l], dims[l + 1]);
    }

    int gx = (NN + 127) / 128;     // gemm row-blocks
    size_t slotbytes = (size_t)NSLOT * 1024 * 4;

    // ---- layer 0: mgemm->Hh ; agg(+b0, BN-fused)->bufA ; bnfin ; norm16
    {
        dim3 grid(gx, 128 / 64);
        k_mgemm<4, true, false><<<grid, 256, 0, stream>>>(x16, Wp[0], Hh, NN, 128, 128, dis, nullptr, nullptr);
        hipMemsetAsync(bnslots, 0, slotbytes, stream);
        k_agg_h<16, false, true><<<(NN + 15) / 16, 256, 0, stream>>>(
            (const uint4*)Hh, bufA, rowptr, degcnt, colv, dis, bp[0], bnslots);
        k_bnfin<<<1, 256, 0, stream>>>(bnslots, gp[0], bep[0], bnAB, 128);
        int total4 = NN * 128 / 4;
        k_norm16<<<(total4 + 255) / 256, 256, 0, stream>>>(
            (const float4*)bufA, bnAB, (uint2*)act16, 128, total4);
    }
    // ---- layer 1 (agg first): scale16->Hh ; agg OUT16->act16 ; mgemm(+b1, BN)->bufA ; bnfin ; norm16
    {
        k_scale16<<<(NN * 16 + 255) / 256, 256, 0, stream>>>(
            (const uint4*)act16, dis, (uint4*)Hh);
        k_agg_h<16, true, false><<<(NN + 15) / 16, 256, 0, stream>>>(
            (const uint4*)Hh, act16, rowptr, degcnt, colv, dis, nullptr, nullptr);
        hipMemsetAsync(bnslots, 0, slotbytes, stream);
        dim3 grid(gx, 256 / 64);
        k_mgemm<4, false, true><<<grid, 256, 0, stream>>>(act16, Wp[1], bufA, NN, 128, 256, nullptr, bp[1], bnslots);
        k_bnfin<<<1, 256, 0, stream>>>(bnslots, gp[1], bep[1], bnAB, 256);
        int total4 = NN * 256 / 4;
        k_norm16<<<(total4 + 255) / 256, 256, 0, stream>>>(
            (const float4*)bufA, bnAB, (uint2*)act16, 256, total4);
    }
    // ---- layer 2: mgemm->Hh ; agg(+b2, BN)->bufA ; bnfin ; norm16
    {
        dim3 grid(gx, 128 / 64);
        k_mgemm<4, true, false><<<grid, 256, 0, stream>>>(act16, Wp[2], Hh, NN, 256, 128, dis, nullptr, nullptr);
        hipMemsetAsync(bnslots, 0, slotbytes, stream);
        k_agg_h<16, false, true><<<(NN + 15) / 16, 256, 0, stream>>>(
            (const uint4*)Hh, bufA, rowptr, degcnt, colv, dis, bp[2], bnslots);
        k_bnfin<<<1, 256, 0, stream>>>(bnslots, gp[2], bep[2], bnAB, 128);
        int total4 = NN * 128 / 4;
        k_norm16<<<(total4 + 255) / 256, 256, 0, stream>>>(
            (const float4*)bufA, bnAB, (uint2*)act16, 128, total4);
    }
    // ---- layer 3 (d=64): mgemm->Hh ; agg(+b3, BN)->bufA ; bnfin ; norm16
    {
        dim3 grid(gx, 64 / 64);
        k_mgemm<4, true, false><<<grid, 256, 0, stream>>>(act16, Wp[3], Hh, NN, 128, 64, dis, nullptr, nullptr);
        hipMemsetAsync(bnslots, 0, slotbytes, stream);
        k_agg_h<8, false, true><<<(NN + 31) / 32, 256, 0, stream>>>(
            (const uint4*)Hh, bufA, rowptr, degcnt, colv, dis, bp[3], bnslots);
        k_bnfin<<<1, 256, 0, stream>>>(bnslots, gp[3], bep[3], bnAB, 64);
        int total4 = NN * 64 / 4;
        k_norm16<<<(total4 + 255) / 256, 256, 0, stream>>>(
            (const float4*)bufA, bnAB, (uint2*)act16, 64, total4);
    }
    // ---- layer 4 (d=32): mgemm->Hh ; agg(+b4, BN)->bufA ; bnfin ; norm16
    {
        dim3 grid(gx, 1);
        k_mgemm<2, true, false><<<grid, 256, 0, stream>>>(act16, Wp[4], Hh, NN, 64, 32, dis, nullptr, nullptr);
        hipMemsetAsync(bnslots, 0, slotbytes, stream);
        k_agg_h<4, false, true><<<(NN + 63) / 64, 256, 0, stream>>>(
            (const uint4*)Hh, bufA, rowptr, degcnt, colv, dis, bp[4], bnslots);
        k_bnfin<<<1, 256, 0, stream>>>(bnslots, gp[4], bep[4], bnAB, 32);
        int total4 = NN * 32 / 4;
        k_norm16<<<(total4 + 255) / 256, 256, 0, stream>>>(
            (const float4*)bufA, bnAB, (uint2*)act16, 32, total4);
    }

    size_t edgeThreads = (size_t)EE * 4;
    k_edge16<<<(unsigned)((edgeThreads + 255) / 256), 256, 0, stream>>>(
        (const uint4*)act16, srcv, dstv, fcw, fcb, (float*)d_out);
}

// Round 9
// 1015.137 us; speedup vs baseline: 2.7610x; 2.7610x over previous
//
#include <hip/hip_runtime.h>
#include <hip/hip_fp16.h>
#include <cstddef>

#define NN 100000
#define EE 3200000
#define EPSB 1e-5f
#define NB 391      // buckets = ceil(NN/256)
#define BCAP 10240  // per-bucket edge capacity
#define BNBLK 512   // BN partial blocks (atomic-free tree reduce)

typedef _Float16 half8 __attribute__((ext_vector_type(8)));
typedef float floatx4 __attribute__((ext_vector_type(4)));

// ---------------------------------------------------------------- CSR build
// packed record: src (17 bits) | dst&255 (8 bits) << 17

__global__ __launch_bounds__(256) void k_bscat(const int* __restrict__ src,
                                               const int* __restrict__ dst,
                                               int* __restrict__ bcur,
                                               unsigned* __restrict__ barr) {
    __shared__ int hist[NB];
    __shared__ int base[NB];
    int tid = threadIdx.x;
    for (int b = tid; b < NB; b += 256) hist[b] = 0;
    __syncthreads();
    int e0 = blockIdx.x * 4096;
    int d[16], s[16];
    #pragma unroll
    for (int j = 0; j < 16; j++) {
        int e = e0 + j * 256 + tid;
        if (e < EE) {
            d[j] = dst[e];
            s[j] = src[e];
            atomicAdd(&hist[d[j] >> 8], 1);
        } else d[j] = -1;
    }
    __syncthreads();
    for (int b = tid; b < NB; b += 256) {
        int c = hist[b];
        base[b] = (c > 0) ? atomicAdd(&bcur[b], c) : 0;
        hist[b] = 0;
    }
    __syncthreads();
    #pragma unroll
    for (int j = 0; j < 16; j++) {
        if (d[j] >= 0) {
            int b = d[j] >> 8;
            int r = atomicAdd(&hist[b], 1);
            barr[(size_t)b * BCAP + base[b] + r] =
                (unsigned)s[j] | ((unsigned)(d[j] & 255) << 17);
        }
    }
}

// per-bucket degree histogram -> coalesced degcnt + dis
__global__ __launch_bounds__(1024) void k_bdeg(const int* __restrict__ bcur,
                                               const unsigned* __restrict__ barr,
                                               int* __restrict__ degcnt,
                                               float* __restrict__ dis) {
    __shared__ int h[256];
    int b = blockIdx.x;
    if (threadIdx.x < 256) h[threadIdx.x] = 0;
    __syncthreads();
    int cnt = bcur[b];
    const unsigned* p = barr + (size_t)b * BCAP;
    for (int t = threadIdx.x; t < cnt; t += 1024)
        atomicAdd(&h[(p[t] >> 17) & 255], 1);
    __syncthreads();
    if (threadIdx.x < 256) {
        int node = (b << 8) + threadIdx.x;
        if (node < NN) {
            int dg = h[threadIdx.x];
            degcnt[node] = dg;
            dis[node] = rsqrtf((float)dg + 1.0f);
        }
    }
}

__global__ __launch_bounds__(1024) void k_place(const int* __restrict__ bcur,
                                                const unsigned* __restrict__ barr,
                                                const int* __restrict__ rowptr,
                                                int* __restrict__ col) {
    __shared__ int cur[256];
    int b = blockIdx.x;
    if (threadIdx.x < 256) {
        int node = (b << 8) + threadIdx.x;
        cur[threadIdx.x] = (node < NN) ? rowptr[node] : 0;
    }
    __syncthreads();
    int cnt = bcur[b];
    const unsigned* p = barr + (size_t)b * BCAP;
    for (int t = threadIdx.x; t < cnt; t += 1024) {
        unsigned e = p[t];
        int pos = atomicAdd(&cur[(e >> 17) & 255], 1);
        col[pos] = (int)(e & 0x1FFFFu);
    }
}

__global__ void k_scan_block(const int* __restrict__ in, int* __restrict__ out,
                             int* __restrict__ blksum, int n) {
    __shared__ int s[1024];
    int i = blockIdx.x * 1024 + threadIdx.x;
    int v = (i < n) ? in[i] : 0;
    s[threadIdx.x] = v;
    __syncthreads();
    for (int off = 1; off < 1024; off <<= 1) {
        int t = (threadIdx.x >= off) ? s[threadIdx.x - off] : 0;
        __syncthreads();
        s[threadIdx.x] += t;
        __syncthreads();
    }
    if (i < n) out[i] = s[threadIdx.x] - v;  // exclusive
    if (threadIdx.x == 1023) blksum[blockIdx.x] = s[1023];
}

__global__ void k_scan_top(int* __restrict__ blksum, int nb) {
    if (threadIdx.x == 0) {
        int acc = 0;
        for (int b = 0; b < nb; b++) { int v = blksum[b]; blksum[b] = acc; acc += v; }
    }
}

__global__ void k_scan_add(int* __restrict__ out, const int* __restrict__ blksum, int n) {
    int i = blockIdx.x * 1024 + threadIdx.x;
    if (i < n) out[i] += blksum[blockIdx.x];
}

// ---------------------------------------------------------------- casts / packing

__global__ void k_f2h(const float4* __restrict__ in, uint2* __restrict__ out, int n4) {
    int t = blockIdx.x * blockDim.x + threadIdx.x;
    if (t >= n4) return;
    float4 v = in[t];
    union { __half2 h; unsigned u; } a, b;
    a.h = __floats2half2_rn(v.x, v.y);
    b.h = __floats2half2_rn(v.z, v.w);
    out[t] = make_uint2(a.u, b.u);
}

// all 5 weight matrices -> transposed fp16 packs, one launch
__global__ void k_wpack_all(const float* __restrict__ W0, const float* __restrict__ W1,
                            const float* __restrict__ W2, const float* __restrict__ W3,
                            const float* __restrict__ W4, __half* __restrict__ Wp) {
    const int offs[6] = {0, 16384, 49152, 81920, 90112, 92160};
    const int Ks[5] = {128, 128, 256, 128, 64};
    const int Ns[5] = {128, 256, 128, 64, 32};
    const float* Ws[5] = {W0, W1, W2, W3, W4};
    int t = blockIdx.x * blockDim.x + threadIdx.x;
    if (t >= 92160) return;
    int l = 0;
    while (t >= offs[l + 1]) l++;
    int local = t - offs[l];
    int N = Ns[l], K = Ks[l];
    int k = local / N, n = local - k * N;
    Wp[(size_t)offs[l] + (size_t)n * K + k] = __float2half(Ws[l][local]);
}

// ---------------------------------------------------------------- MFMA GEMM
// OUT16: C fp16 = dis[row]*acc (staged agg operand). else: C fp32 = acc+bias.

template<int NT, bool OUT16>
__global__ __launch_bounds__(256) void k_mgemm(const __half* __restrict__ A,
                                               const __half* __restrict__ Wp,
                                               void* __restrict__ Cv,
                                               int M, int K, int N,
                                               const float* __restrict__ dis,
                                               const float* __restrict__ bias) {
    constexpr int TN = NT * 16;
    __shared__ __half Ash[128][40];
    __shared__ __half Bsh[TN][40];
    int tid  = threadIdx.x;
    int wave = tid >> 6;
    int lane = tid & 63;
    int quad = lane >> 4;
    int l16  = lane & 15;
    int bm = blockIdx.x * 128;
    int bn = blockIdx.y * TN;

    floatx4 acc[2][NT];
    #pragma unroll
    for (int mt = 0; mt < 2; mt++)
        #pragma unroll
        for (int nt = 0; nt < NT; nt++)
            acc[mt][nt] = (floatx4){0.f, 0.f, 0.f, 0.f};

    for (int k0 = 0; k0 < K; k0 += 32) {
        #pragma unroll
        for (int it = 0; it < 2; it++) {
            int u = tid + it * 256;
            int row = u >> 2, seg = u & 3;
            int grow = bm + row;
            uint4 v = make_uint4(0, 0, 0, 0);
            if (grow < M) v = *(const uint4*)&A[(size_t)grow * K + k0 + seg * 8];
            *(uint4*)&Ash[row][seg * 8] = v;
        }
        if (tid < TN * 4) {
            int n = tid >> 2, seg = tid & 3;
            uint4 v = *(const uint4*)&Wp[(size_t)(bn + n) * K + k0 + seg * 8];
            *(uint4*)&Bsh[n][seg * 8] = v;
        }
        __syncthreads();
        half8 a[2], b[NT];
        #pragma unroll
        for (int mt = 0; mt < 2; mt++)
            a[mt] = *(const half8*)&Ash[wave * 32 + mt * 16 + l16][quad * 8];
        #pragma unroll
        for (int nt = 0; nt < NT; nt++)
            b[nt] = *(const half8*)&Bsh[nt * 16 + l16][quad * 8];
        #pragma unroll
        for (int mt = 0; mt < 2; mt++)
            #pragma unroll
            for (int nt = 0; nt < NT; nt++)
                acc[mt][nt] = __builtin_amdgcn_mfma_f32_16x16x32_f16(
                    a[mt], b[nt], acc[mt][nt], 0, 0, 0);
        __syncthreads();
    }

    #pragma unroll
    for (int mt = 0; mt < 2; mt++) {
        #pragma unroll
        for (int r = 0; r < 4; r++) {
            int grow = bm + wave * 32 + mt * 16 + quad * 4 + r;
            if (grow >= M) continue;
            if (OUT16) {
                float ds = dis[grow];
                __half* C = (__half*)Cv;
                #pragma unroll
                for (int nt = 0; nt < NT; nt++) {
                    int gcol = bn + nt * 16 + l16;
                    C[(size_t)grow * N + gcol] = __float2half(ds * acc[mt][nt][r]);
                }
            } else {
                float* C = (float*)Cv;
                #pragma unroll
                for (int nt = 0; nt < NT; nt++) {
                    int gcol = bn + nt * 16 + l16;
                    C[(size_t)grow * N + gcol] = acc[mt][nt][r] + bias[gcol];
                }
            }
        }
    }
}

// layer-1 staging: Hh = fp16(dis[i] * act16[i][:]), d=128 (16 uint4/row)
__global__ void k_scale16(const uint4* __restrict__ X, const float* __restrict__ dis,
                          uint4* __restrict__ out) {
    int t = blockIdx.x * blockDim.x + threadIdx.x;
    if (t >= NN * 16) return;
    int row = t >> 4;
    float ds = dis[row];
    uint4 v = X[t];
    const __half2* hp = (const __half2*)&v;
    uint4 o;
    __half2* op = (__half2*)&o;
    #pragma unroll
    for (int k = 0; k < 4; k++) {
        float2 f = __half22float2(hp[k]);
        op[k] = __floats2half2_rn(ds * f.x, ds * f.y);
    }
    out[t] = o;
}

// ---------------------------------------------------------------- aggregation
// Full-row gather (16B/thread, TPN = d/8 threads/node). Lessons pinned:
//  - R7: never slice a row below L2-line granularity (32B stripes -> 4x FETCH)
//  - R8: no global atomics in the epilogue (6.4M atomics -> 8x slowdown)

__device__ __forceinline__ void acc_row(float* acc, const uint4& r) {
    const __half2* hp = (const __half2*)&r;
    #pragma unroll
    for (int k = 0; k < 4; k++) {
        float2 f2 = __half22float2(hp[k]);
        acc[2 * k]     += f2.x;
        acc[2 * k + 1] += f2.y;
    }
}

template<int TPN, bool OUT16>
__global__ __launch_bounds__(256) void k_agg_h(const uint4* __restrict__ Hs,
                                               void* __restrict__ outv,
                                               const int* __restrict__ rowptr,
                                               const int* __restrict__ degcnt,
                                               const int* __restrict__ colv,
                                               const float* __restrict__ dis,
                                               const float* __restrict__ bias) {
    constexpr int G = 256 / TPN;
    int g    = threadIdx.x / TPN;
    int lane = threadIdx.x % TPN;
    int i = blockIdx.x * G + g;
    if (i >= NN) return;
    int beg = rowptr[i];
    int cnt = degcnt[i];
    const uint4* base = Hs + lane;
    float acc[8] = {};
    int e = 0;
    for (; e + 8 <= cnt; e += 8) {
        int c[8];
        #pragma unroll
        for (int j = 0; j < 8; j++) c[j] = colv[beg + e + j];
        uint4 r[8];
        #pragma unroll
        for (int j = 0; j < 8; j++) r[j] = base[(size_t)c[j] * TPN];
        #pragma unroll
        for (int j = 0; j < 8; j++) acc_row(acc, r[j]);
    }
    for (; e < cnt; e++) {
        uint4 r = base[(size_t)colv[beg + e] * TPN];
        acc_row(acc, r);
    }
    uint4 rs = base[(size_t)i * TPN];  // self-loop
    acc_row(acc, rs);
    float ds = dis[i];
    float o[8];
    #pragma unroll
    for (int k = 0; k < 8; k++) o[k] = ds * acc[k];
    if (OUT16) {
        uint4 ov;
        __half2* op = (__half2*)&ov;
        #pragma unroll
        for (int k = 0; k < 4; k++) op[k] = __floats2half2_rn(o[2 * k], o[2 * k + 1]);
        ((uint4*)outv)[(size_t)i * TPN + lane] = ov;
    } else {
        float4 b0 = ((const float4*)bias)[lane * 2];
        float4 b1 = ((const float4*)bias)[lane * 2 + 1];
        o[0] += b0.x; o[1] += b0.y; o[2] += b0.z; o[3] += b0.w;
        o[4] += b1.x; o[5] += b1.y; o[6] += b1.z; o[7] += b1.w;
        float4* out = (float4*)outv;
        size_t ob = (size_t)i * (2 * TPN) + lane * 2;
        out[ob]     = make_float4(o[0], o[1], o[2], o[3]);
        out[ob + 1] = make_float4(o[4], o[5], o[6], o[7]);
    }
}

// ---------------------------------------------------------------- BatchNorm
// Atomic-free two-phase tree: per-block partials (plain stores) + single-block
// final reduce. (R6/R8 lesson: contended global atomics are the enemy.)

template<int D>
__global__ __launch_bounds__(256) void k_bnpart(const float4* __restrict__ X4,
                                                float* __restrict__ partial) {
    constexpr int Q   = D / 4;
    constexpr int RPI = 256 / Q;
    int tq = threadIdx.x % Q;
    int rg = threadIdx.x / Q;
    int chunk = (NN + BNBLK - 1) / BNBLK;
    int r0 = blockIdx.x * chunk;
    int r1 = r0 + chunk; if (r1 > NN) r1 = NN;
    float4 s  = {0.f, 0.f, 0.f, 0.f};
    float4 s2 = {0.f, 0.f, 0.f, 0.f};
    for (int r = r0 + rg; r < r1; r += RPI) {
        float4 v = X4[(size_t)r * Q + tq];
        s.x += v.x; s.y += v.y; s.z += v.z; s.w += v.w;
        s2.x += v.x * v.x; s2.y += v.y * v.y; s2.z += v.z * v.z; s2.w += v.w * v.w;
    }
    __shared__ float4 ls[256], ls2[256];
    ls[threadIdx.x] = s; ls2[threadIdx.x] = s2;
    __syncthreads();
    if (threadIdx.x < Q) {
        float4 a = ls[threadIdx.x], b = ls2[threadIdx.x];
        #pragma unroll
        for (int g = 1; g < RPI; g++) {
            float4 u = ls[g * Q + threadIdx.x], w = ls2[g * Q + threadIdx.x];
            a.x += u.x; a.y += u.y; a.z += u.z; a.w += u.w;
            b.x += w.x; b.y += w.y; b.z += w.z; b.w += w.w;
        }
        *(float4*)&partial[(size_t)blockIdx.x * 2 * D + threadIdx.x * 4]     = a;
        *(float4*)&partial[(size_t)blockIdx.x * 2 * D + D + threadIdx.x * 4] = b;
    }
}

template<int D>
__global__ void k_bnfin2(const float* __restrict__ partial, const float* __restrict__ g,
                         const float* __restrict__ be, float* __restrict__ AB) {
    int f = threadIdx.x;
    if (f < D) {
        float sum = 0.f, sq = 0.f;
        for (int b = 0; b < BNBLK; b++) {
            sum += partial[(size_t)b * 2 * D + f];
            sq  += partial[(size_t)b * 2 * D + D + f];
        }
        float mu  = sum / (float)NN;
        float var = sq / (float)NN - mu * mu;
        var = fmaxf(var, 0.f);
        float inv = rsqrtf(var + EPSB);
        float a = g[f] * inv;
        AB[f]     = a;
        AB[D + f] = be[f] - mu * a;
    }
}

__global__ void k_norm16(const float4* __restrict__ X, const float* __restrict__ AB,
                         uint2* __restrict__ Y, int d, int total4) {
    int t = blockIdx.x * blockDim.x + threadIdx.x;
    if (t >= total4) return;
    int f0 = (t * 4) & (d - 1);
    float4 v = X[t];
    float a0 = AB[f0],     a1 = AB[f0 + 1], a2 = AB[f0 + 2], a3 = AB[f0 + 3];
    float c0 = AB[d + f0], c1 = AB[d + f0 + 1], c2 = AB[d + f0 + 2], c3 = AB[d + f0 + 3];
    float o0 = fmaxf(v.x * a0 + c0, 0.f);
    float o1 = fmaxf(v.y * a1 + c1, 0.f);
    float o2 = fmaxf(v.z * a2 + c2, 0.f);
    float o3 = fmaxf(v.w * a3 + c3, 0.f);
    union { __half2 h; unsigned u; } p, q;
    p.h = __floats2half2_rn(o0, o1);
    q.h = __floats2half2_rn(o2, o3);
    Y[t] = make_uint2(p.u, q.u);
}

// ---------------------------------------------------------------- final edge MLP

__global__ __launch_bounds__(256) void k_edge16(const uint4* __restrict__ X,
                                                const int* __restrict__ src,
                                                const int* __restrict__ dst,
                                                const float* __restrict__ fcw,
                                                const float* __restrict__ fcb,
                                                float* __restrict__ out) {
    int lane = threadIdx.x & 3;
    size_t t = (size_t)blockIdx.x * 256 + threadIdx.x;
    int eid = (int)(t >> 2);
    if (eid >= EE) return;
    int s = src[eid], d = dst[eid];
    uint4 av = X[(size_t)s * 4 + lane];
    uint4 bv = X[(size_t)d * 4 + lane];
    const __half2* ap = (const __half2*)&av;
    const __half2* bp2 = (const __half2*)&bv;
    float v = 0.f;
    #pragma unroll
    for (int k = 0; k < 4; k++) {
        float2 fa = __half22float2(ap[k]);
        float2 fb = __half22float2(bp2[k]);
        float w0 = fcw[lane * 8 + 2 * k];
        float w1 = fcw[lane * 8 + 2 * k + 1];
        v += fa.x * fb.x * w0 + fa.y * fb.y * w1;
    }
    v += __shfl_xor(v, 1, 4);
    v += __shfl_xor(v, 2, 4);
    if (lane == 0) out[eid] = 1.f / (1.f + expf(-(v + fcb[0])));
}

// ---------------------------------------------------------------- launch

extern "C" void kernel_launch(void* const* d_in, const int* in_sizes, int n_in,
                              void* d_out, int out_size, void* d_ws, size_t ws_size,
                              hipStream_t stream) {
    const float* x0 = (const float*)d_in[0];
    const int* ei   = (const int*)d_in[1];
    const int* srcv = ei;
    const int* dstv = ei + EE;
    const float *W[5], *bp[5], *gp[5], *bep[5];
    int idx = 2;
    for (int l = 0; l < 5; l++) {
        W[l]   = (const float*)d_in[idx++];
        bp[l]  = (const float*)d_in[idx++];
        gp[l]  = (const float*)d_in[idx++];
        bep[l] = (const float*)d_in[idx++];
    }
    const float* fcw = (const float*)d_in[22];
    const float* fcb = (const float*)d_in[23];

    char* ws = (char*)d_ws;
    size_t off = 0;
    auto alloc = [&](size_t bytes) -> void* {
        void* p = ws + off;
        off = (off + bytes + 255) & ~(size_t)255;
        return p;
    };
    float*    bufA    = (float*)   alloc((size_t)NN * 256 * 4);
    __half*   act16   = (__half*)  alloc((size_t)NN * 256 * 2);
    __half*   x16     = (__half*)  alloc((size_t)NN * 128 * 2);
    __half*   Hh      = (__half*)  alloc((size_t)NN * 128 * 2);
    unsigned* barr    = (unsigned*)alloc((size_t)NB * BCAP * 4);
    int*      colv    = (int*)     alloc((size_t)EE * 4);
    int*      rowptr  = (int*)     alloc((size_t)NN * 4);
    int*      degcnt  = (int*)     alloc((size_t)NN * 4);
    float*    dis     = (float*)   alloc((size_t)NN * 4);
    int*      bcur    = (int*)     alloc((size_t)NB * 4);
    int*      scnblk  = (int*)     alloc(4096);
    float*    bnpart  = (float*)   alloc((size_t)BNBLK * 512 * 4);  // 1 MB
    float*    bnAB    = (float*)   alloc(512 * 4);
    __half*   Wp      = (__half*)  alloc((size_t)92160 * 2);
    const int woff[5] = {0, 16384, 49152, 81920, 90112};

    // ---- CSR build (binned counting sort)
    hipMemsetAsync(bcur, 0, (size_t)NB * 4, stream);
    k_bscat<<<(EE + 4095) / 4096, 256, 0, stream>>>(srcv, dstv, bcur, barr);
    k_bdeg<<<NB, 1024, 0, stream>>>(bcur, barr, degcnt, dis);
    int nScanBlk = (NN + 1023) / 1024;
    k_scan_block<<<nScanBlk, 1024, 0, stream>>>(degcnt, rowptr, scnblk, NN);
    k_scan_top<<<1, 64, 0, stream>>>(scnblk, nScanBlk);
    k_scan_add<<<nScanBlk, 1024, 0, stream>>>(rowptr, scnblk, NN);
    k_place<<<NB, 1024, 0, stream>>>(bcur, barr, rowptr, colv);

    // ---- casts / weight packs
    k_f2h<<<(NN * 128 / 4 + 255) / 256, 256, 0, stream>>>(
        (const float4*)x0, (uint2*)x16, NN * 128 / 4);
    k_wpack_all<<<(92160 + 255) / 256, 256, 0, stream>>>(W[0], W[1], W[2], W[3], W[4], Wp);

    int gx = (NN + 127) / 128;

    // ---- layer 0: mgemm->Hh ; agg(+b0)->bufA ; bnpart/bnfin2 ; norm16
    {
        dim3 grid(gx, 128 / 64);
        k_mgemm<4, true><<<grid, 256, 0, stream>>>(x16, Wp + woff[0], Hh, NN, 128, 128, dis, nullptr);
        k_agg_h<16, false><<<(NN + 15) / 16, 256, 0, stream>>>(
            (const uint4*)Hh, bufA, rowptr, degcnt, colv, dis, bp[0]);
        k_bnpart<128><<<BNBLK, 256, 0, stream>>>((const float4*)bufA, bnpart);
        k_bnfin2<128><<<1, 256, 0, stream>>>(bnpart, gp[0], bep[0], bnAB);
        int total4 = NN * 128 / 4;
        k_norm16<<<(total4 + 255) / 256, 256, 0, stream>>>(
            (const float4*)bufA, bnAB, (uint2*)act16, 128, total4);
    }
    // ---- layer 1 (agg first): scale16->Hh ; agg OUT16->act16 ; mgemm(+b1)->bufA ; bn ; norm16
    {
        k_scale16<<<(NN * 16 + 255) / 256, 256, 0, stream>>>(
            (const uint4*)act16, dis, (uint4*)Hh);
        k_agg_h<16, true><<<(NN + 15) / 16, 256, 0, stream>>>(
            (const uint4*)Hh, act16, rowptr, degcnt, colv, dis, nullptr);
        dim3 grid(gx, 256 / 64);
        k_mgemm<4, false><<<grid, 256, 0, stream>>>(act16, Wp + woff[1], bufA, NN, 128, 256, nullptr, bp[1]);
        k_bnpart<256><<<BNBLK, 256, 0, stream>>>((const float4*)bufA, bnpart);
        k_bnfin2<256><<<1, 256, 0, stream>>>(bnpart, gp[1], bep[1], bnAB);
        int total4 = NN * 256 / 4;
        k_norm16<<<(total4 + 255) / 256, 256, 0, stream>>>(
            (const float4*)bufA, bnAB, (uint2*)act16, 256, total4);
    }
    // ---- layer 2
    {
        dim3 grid(gx, 128 / 64);
        k_mgemm<4, true><<<grid, 256, 0, stream>>>(act16, Wp + woff[2], Hh, NN, 256, 128, dis, nullptr);
        k_agg_h<16, false><<<(NN + 15) / 16, 256, 0, stream>>>(
            (const uint4*)Hh, bufA, rowptr, degcnt, colv, dis, bp[2]);
        k_bnpart<128><<<BNBLK, 256, 0, stream>>>((const float4*)bufA, bnpart);
        k_bnfin2<128><<<1, 256, 0, stream>>>(bnpart, gp[2], bep[2], bnAB);
        int total4 = NN * 128 / 4;
        k_norm16<<<(total4 + 255) / 256, 256, 0, stream>>>(
            (const float4*)bufA, bnAB, (uint2*)act16, 128, total4);
    }
    // ---- layer 3 (d=64)
    {
        dim3 grid(gx, 64 / 64);
        k_mgemm<4, true><<<grid, 256, 0, stream>>>(act16, Wp + woff[3], Hh, NN, 128, 64, dis, nullptr);
        k_agg_h<8, false><<<(NN + 31) / 32, 256, 0, stream>>>(
            (const uint4*)Hh, bufA, rowptr, degcnt, colv, dis, bp[3]);
        k_bnpart<64><<<BNBLK, 256, 0, stream>>>((const float4*)bufA, bnpart);
        k_bnfin2<64><<<1, 256, 0, stream>>>(bnpart, gp[3], bep[3], bnAB);
        int total4 = NN * 64 / 4;
        k_norm16<<<(total4 + 255) / 256, 256, 0, stream>>>(
            (const float4*)bufA, bnAB, (uint2*)act16, 64, total4);
    }
    // ---- layer 4 (d=32)
    {
        dim3 grid(gx, 1);
        k_mgemm<2, true><<<grid, 256, 0, stream>>>(act16, Wp + woff[4], Hh, NN, 64, 32, dis, nullptr);
        k_agg_h<4, false><<<(NN + 63) / 64, 256, 0, stream>>>(
            (const uint4*)Hh, bufA, rowptr, degcnt, colv, dis, bp[4]);
        k_bnpart<32><<<BNBLK, 256, 0, stream>>>((const float4*)bufA, bnpart);
        k_bnfin2<32><<<1, 256, 0, stream>>>(bnpart, gp[4], bep[4], bnAB);
        int total4 = NN * 32 / 4;
        k_norm16<<<(total4 + 255) / 256, 256, 0, stream>>>(
            (const float4*)bufA, bnAB, (uint2*)act16, 32, total4);
    }

    size_t edgeThreads = (size_t)EE * 4;
    k_edge16<<<(unsigned)((edgeThreads + 255) / 256), 256, 0, stream>>>(
        (const uint4*)act16, srcv, dstv, fcw, fcb, (float*)d_out);
}

// Round 10
// 1003.815 us; speedup vs baseline: 2.7921x; 1.0113x over previous
//
#include <hip/hip_runtime.h>
#include <hip/hip_fp16.h>
#include <cstddef>

#define NN 100000
#define EE 3200000
#define EPSB 1e-5f
#define NB 391      // buckets = ceil(NN/256)
#define BCAP 10240  // per-bucket edge capacity
#define BNBLK 512   // BN partial blocks (atomic-free tree reduce)

typedef _Float16 half8 __attribute__((ext_vector_type(8)));
typedef float floatx4 __attribute__((ext_vector_type(4)));

// ---------------------------------------------------------------- CSR build
// packed record: src (17 bits) | dst&255 (8 bits) << 17

__global__ __launch_bounds__(256) void k_bscat(const int* __restrict__ src,
                                               const int* __restrict__ dst,
                                               int* __restrict__ bcur,
                                               unsigned* __restrict__ barr) {
    __shared__ int hist[NB];
    __shared__ int base[NB];
    int tid = threadIdx.x;
    for (int b = tid; b < NB; b += 256) hist[b] = 0;
    __syncthreads();
    int e0 = blockIdx.x * 4096;
    int d[16], s[16];
    #pragma unroll
    for (int j = 0; j < 16; j++) {
        int e = e0 + j * 256 + tid;
        if (e < EE) {
            d[j] = dst[e];
            s[j] = src[e];
            atomicAdd(&hist[d[j] >> 8], 1);
        } else d[j] = -1;
    }
    __syncthreads();
    for (int b = tid; b < NB; b += 256) {
        int c = hist[b];
        base[b] = (c > 0) ? atomicAdd(&bcur[b], c) : 0;
        hist[b] = 0;
    }
    __syncthreads();
    #pragma unroll
    for (int j = 0; j < 16; j++) {
        if (d[j] >= 0) {
            int b = d[j] >> 8;
            int r = atomicAdd(&hist[b], 1);
            barr[(size_t)b * BCAP + base[b] + r] =
                (unsigned)s[j] | ((unsigned)(d[j] & 255) << 17);
        }
    }
}

__global__ __launch_bounds__(1024) void k_bdeg(const int* __restrict__ bcur,
                                               const unsigned* __restrict__ barr,
                                               int* __restrict__ degcnt,
                                               float* __restrict__ dis) {
    __shared__ int h[256];
    int b = blockIdx.x;
    if (threadIdx.x < 256) h[threadIdx.x] = 0;
    __syncthreads();
    int cnt = bcur[b];
    const unsigned* p = barr + (size_t)b * BCAP;
    for (int t = threadIdx.x; t < cnt; t += 1024)
        atomicAdd(&h[(p[t] >> 17) & 255], 1);
    __syncthreads();
    if (threadIdx.x < 256) {
        int node = (b << 8) + threadIdx.x;
        if (node < NN) {
            int dg = h[threadIdx.x];
            degcnt[node] = dg;
            dis[node] = rsqrtf((float)dg + 1.0f);
        }
    }
}

__global__ __launch_bounds__(1024) void k_place(const int* __restrict__ bcur,
                                                const unsigned* __restrict__ barr,
                                                const int* __restrict__ rowptr,
                                                int* __restrict__ col) {
    __shared__ int cur[256];
    int b = blockIdx.x;
    if (threadIdx.x < 256) {
        int node = (b << 8) + threadIdx.x;
        cur[threadIdx.x] = (node < NN) ? rowptr[node] : 0;
    }
    __syncthreads();
    int cnt = bcur[b];
    const unsigned* p = barr + (size_t)b * BCAP;
    for (int t = threadIdx.x; t < cnt; t += 1024) {
        unsigned e = p[t];
        int pos = atomicAdd(&cur[(e >> 17) & 255], 1);
        col[pos] = (int)(e & 0x1FFFFu);
    }
}

__global__ void k_scan_block(const int* __restrict__ in, int* __restrict__ out,
                             int* __restrict__ blksum, int n) {
    __shared__ int s[1024];
    int i = blockIdx.x * 1024 + threadIdx.x;
    int v = (i < n) ? in[i] : 0;
    s[threadIdx.x] = v;
    __syncthreads();
    for (int off = 1; off < 1024; off <<= 1) {
        int t = (threadIdx.x >= off) ? s[threadIdx.x - off] : 0;
        __syncthreads();
        s[threadIdx.x] += t;
        __syncthreads();
    }
    if (i < n) out[i] = s[threadIdx.x] - v;  // exclusive
    if (threadIdx.x == 1023) blksum[blockIdx.x] = s[1023];
}

__global__ void k_scan_top(int* __restrict__ blksum, int nb) {
    if (threadIdx.x == 0) {
        int acc = 0;
        for (int b = 0; b < nb; b++) { int v = blksum[b]; blksum[b] = acc; acc += v; }
    }
}

__global__ void k_scan_add(int* __restrict__ out, const int* __restrict__ blksum, int n) {
    int i = blockIdx.x * 1024 + threadIdx.x;
    if (i < n) out[i] += blksum[blockIdx.x];
}

// ---------------------------------------------------------------- casts / packing

__global__ void k_f2h(const float4* __restrict__ in, uint2* __restrict__ out, int n4) {
    int t = blockIdx.x * blockDim.x + threadIdx.x;
    if (t >= n4) return;
    float4 v = in[t];
    union { __half2 h; unsigned u; } a, b;
    a.h = __floats2half2_rn(v.x, v.y);
    b.h = __floats2half2_rn(v.z, v.w);
    out[t] = make_uint2(a.u, b.u);
}

__global__ void k_wpack_all(const float* __restrict__ W0, const float* __restrict__ W1,
                            const float* __restrict__ W2, const float* __restrict__ W3,
                            const float* __restrict__ W4, __half* __restrict__ Wp) {
    const int offs[6] = {0, 16384, 49152, 81920, 90112, 92160};
    const int Ks[5] = {128, 128, 256, 128, 64};
    const int Ns[5] = {128, 256, 128, 64, 32};
    const float* Ws[5] = {W0, W1, W2, W3, W4};
    int t = blockIdx.x * blockDim.x + threadIdx.x;
    if (t >= 92160) return;
    int l = 0;
    while (t >= offs[l + 1]) l++;
    int local = t - offs[l];
    int N = Ns[l], K = Ks[l];
    int k = local / N, n = local - k * N;
    Wp[(size_t)offs[l] + (size_t)n * K + k] = __float2half(Ws[l][local]);
}

// ---------------------------------------------------------------- MFMA GEMM
// ABN:   A is fp32 conv-out; BN scale/shift+ReLU applied during LDS staging.
// else:  A is fp16 row-major.
// OUT16: C fp16 = dis[row]*acc (staged agg operand). else: C fp32 = acc+bias.

template<int NT, bool OUT16, bool ABN>
__global__ __launch_bounds__(256) void k_mgemm(const void* __restrict__ Av,
                                               const __half* __restrict__ Wp,
                                               void* __restrict__ Cv,
                                               int M, int K, int N,
                                               const float* __restrict__ dis,
                                               const float* __restrict__ bias,
                                               const float* __restrict__ AB) {
    constexpr int TN = NT * 16;
    __shared__ __half Ash[128][40];
    __shared__ __half Bsh[TN][40];
    int tid  = threadIdx.x;
    int wave = tid >> 6;
    int lane = tid & 63;
    int quad = lane >> 4;
    int l16  = lane & 15;
    int bm = blockIdx.x * 128;
    int bn = blockIdx.y * TN;

    floatx4 acc[2][NT];
    #pragma unroll
    for (int mt = 0; mt < 2; mt++)
        #pragma unroll
        for (int nt = 0; nt < NT; nt++)
            acc[mt][nt] = (floatx4){0.f, 0.f, 0.f, 0.f};

    for (int k0 = 0; k0 < K; k0 += 32) {
        #pragma unroll
        for (int it = 0; it < 2; it++) {
            int u = tid + it * 256;
            int row = u >> 2, seg = u & 3;
            int grow = bm + row;
            if (ABN) {
                const float* Af = (const float*)Av;
                int f0 = k0 + seg * 8;
                uint4 o = make_uint4(0, 0, 0, 0);
                if (grow < M) {
                    float4 x0 = *(const float4*)&Af[(size_t)grow * K + f0];
                    float4 x1 = *(const float4*)&Af[(size_t)grow * K + f0 + 4];
                    float4 a0 = *(const float4*)&AB[f0];
                    float4 a1 = *(const float4*)&AB[f0 + 4];
                    float4 c0 = *(const float4*)&AB[K + f0];
                    float4 c1 = *(const float4*)&AB[K + f0 + 4];
                    float h0 = fmaxf(x0.x * a0.x + c0.x, 0.f);
                    float h1 = fmaxf(x0.y * a0.y + c0.y, 0.f);
                    float h2 = fmaxf(x0.z * a0.z + c0.z, 0.f);
                    float h3 = fmaxf(x0.w * a0.w + c0.w, 0.f);
                    float h4 = fmaxf(x1.x * a1.x + c1.x, 0.f);
                    float h5 = fmaxf(x1.y * a1.y + c1.y, 0.f);
                    float h6 = fmaxf(x1.z * a1.z + c1.z, 0.f);
                    float h7 = fmaxf(x1.w * a1.w + c1.w, 0.f);
                    union { __half2 h; unsigned u; } p0, p1, p2, p3;
                    p0.h = __floats2half2_rn(h0, h1);
                    p1.h = __floats2half2_rn(h2, h3);
                    p2.h = __floats2half2_rn(h4, h5);
                    p3.h = __floats2half2_rn(h6, h7);
                    o = make_uint4(p0.u, p1.u, p2.u, p3.u);
                }
                *(uint4*)&Ash[row][seg * 8] = o;
            } else {
                const __half* A = (const __half*)Av;
                uint4 v = make_uint4(0, 0, 0, 0);
                if (grow < M) v = *(const uint4*)&A[(size_t)grow * K + k0 + seg * 8];
                *(uint4*)&Ash[row][seg * 8] = v;
            }
        }
        if (tid < TN * 4) {
            int n = tid >> 2, seg = tid & 3;
            uint4 v = *(const uint4*)&Wp[(size_t)(bn + n) * K + k0 + seg * 8];
            *(uint4*)&Bsh[n][seg * 8] = v;
        }
        __syncthreads();
        half8 a[2], b[NT];
        #pragma unroll
        for (int mt = 0; mt < 2; mt++)
            a[mt] = *(const half8*)&Ash[wave * 32 + mt * 16 + l16][quad * 8];
        #pragma unroll
        for (int nt = 0; nt < NT; nt++)
            b[nt] = *(const half8*)&Bsh[nt * 16 + l16][quad * 8];
        #pragma unroll
        for (int mt = 0; mt < 2; mt++)
            #pragma unroll
            for (int nt = 0; nt < NT; nt++)
                acc[mt][nt] = __builtin_amdgcn_mfma_f32_16x16x32_f16(
                    a[mt], b[nt], acc[mt][nt], 0, 0, 0);
        __syncthreads();
    }

    #pragma unroll
    for (int mt = 0; mt < 2; mt++) {
        #pragma unroll
        for (int r = 0; r < 4; r++) {
            int grow = bm + wave * 32 + mt * 16 + quad * 4 + r;
            if (grow >= M) continue;
            if (OUT16) {
                float ds = dis[grow];
                __half* C = (__half*)Cv;
                #pragma unroll
                for (int nt = 0; nt < NT; nt++) {
                    int gcol = bn + nt * 16 + l16;
                    C[(size_t)grow * N + gcol] = __float2half(ds * acc[mt][nt][r]);
                }
            } else {
                float* C = (float*)Cv;
                #pragma unroll
                for (int nt = 0; nt < NT; nt++) {
                    int gcol = bn + nt * 16 + l16;
                    C[(size_t)grow * N + gcol] = acc[mt][nt][r] + bias[gcol];
                }
            }
        }
    }
}

// L0 fused BN+ReLU+dis-scale: Hh = fp16(dis[i] * relu(a*x+c)), d=128
__global__ void k_nscale(const float* __restrict__ X, const float* __restrict__ AB,
                         const float* __restrict__ dis, uint4* __restrict__ out) {
    int t = blockIdx.x * blockDim.x + threadIdx.x;
    if (t >= NN * 16) return;
    int row = t >> 4;
    int f0 = (t & 15) * 8;
    float ds = dis[row];
    float4 x0 = *(const float4*)&X[(size_t)row * 128 + f0];
    float4 x1 = *(const float4*)&X[(size_t)row * 128 + f0 + 4];
    float4 a0 = *(const float4*)&AB[f0];
    float4 a1 = *(const float4*)&AB[f0 + 4];
    float4 c0 = *(const float4*)&AB[128 + f0];
    float4 c1 = *(const float4*)&AB[128 + f0 + 4];
    float h0 = ds * fmaxf(x0.x * a0.x + c0.x, 0.f);
    float h1 = ds * fmaxf(x0.y * a0.y + c0.y, 0.f);
    float h2 = ds * fmaxf(x0.z * a0.z + c0.z, 0.f);
    float h3 = ds * fmaxf(x0.w * a0.w + c0.w, 0.f);
    float h4 = ds * fmaxf(x1.x * a1.x + c1.x, 0.f);
    float h5 = ds * fmaxf(x1.y * a1.y + c1.y, 0.f);
    float h6 = ds * fmaxf(x1.z * a1.z + c1.z, 0.f);
    float h7 = ds * fmaxf(x1.w * a1.w + c1.w, 0.f);
    union { __half2 h; unsigned u; } p0, p1, p2, p3;
    p0.h = __floats2half2_rn(h0, h1);
    p1.h = __floats2half2_rn(h2, h3);
    p2.h = __floats2half2_rn(h4, h5);
    p3.h = __floats2half2_rn(h6, h7);
    out[t] = make_uint4(p0.u, p1.u, p2.u, p3.u);
}

// ---------------------------------------------------------------- aggregation
// Full-row gather (16B/thread, TPN = d/8 threads/node). Lessons pinned:
//  - R7: never slice a row below L2-line granularity (32B stripes -> 4x FETCH)
//  - R8: no contended global atomics in epilogues (6.4M atomics -> 8x slowdown)

__device__ __forceinline__ void acc_row(float* acc, const uint4& r) {
    const __half2* hp = (const __half2*)&r;
    #pragma unroll
    for (int k = 0; k < 4; k++) {
        float2 f2 = __half22float2(hp[k]);
        acc[2 * k]     += f2.x;
        acc[2 * k + 1] += f2.y;
    }
}

template<int TPN, bool OUT16>
__global__ __launch_bounds__(256) void k_agg_h(const uint4* __restrict__ Hs,
                                               void* __restrict__ outv,
                                               const int* __restrict__ rowptr,
                                               const int* __restrict__ degcnt,
                                               const int* __restrict__ colv,
                                               const float* __restrict__ dis,
                                               const float* __restrict__ bias) {
    constexpr int G = 256 / TPN;
    int g    = threadIdx.x / TPN;
    int lane = threadIdx.x % TPN;
    int i = blockIdx.x * G + g;
    if (i >= NN) return;
    int beg = rowptr[i];
    int cnt = degcnt[i];
    const uint4* base = Hs + lane;
    float acc[8] = {};
    int e = 0;
    for (; e + 8 <= cnt; e += 8) {
        int c[8];
        #pragma unroll
        for (int j = 0; j < 8; j++) c[j] = colv[beg + e + j];
        uint4 r[8];
        #pragma unroll
        for (int j = 0; j < 8; j++) r[j] = base[(size_t)c[j] * TPN];
        #pragma unroll
        for (int j = 0; j < 8; j++) acc_row(acc, r[j]);
    }
    for (; e < cnt; e++) {
        uint4 r = base[(size_t)colv[beg + e] * TPN];
        acc_row(acc, r);
    }
    uint4 rs = base[(size_t)i * TPN];  // self-loop
    acc_row(acc, rs);
    float ds = dis[i];
    float o[8];
    #pragma unroll
    for (int k = 0; k < 8; k++) o[k] = ds * acc[k];
    if (OUT16) {
        uint4 ov;
        __half2* op = (__half2*)&ov;
        #pragma unroll
        for (int k = 0; k < 4; k++) op[k] = __floats2half2_rn(o[2 * k], o[2 * k + 1]);
        ((uint4*)outv)[(size_t)i * TPN + lane] = ov;
    } else {
        float4 b0 = ((const float4*)bias)[lane * 2];
        float4 b1 = ((const float4*)bias)[lane * 2 + 1];
        o[0] += b0.x; o[1] += b0.y; o[2] += b0.z; o[3] += b0.w;
        o[4] += b1.x; o[5] += b1.y; o[6] += b1.z; o[7] += b1.w;
        float4* out = (float4*)outv;
        size_t ob = (size_t)i * (2 * TPN) + lane * 2;
        out[ob]     = make_float4(o[0], o[1], o[2], o[3]);
        out[ob + 1] = make_float4(o[4], o[5], o[6], o[7]);
    }
}

// ---------------------------------------------------------------- BatchNorm
// Atomic-free two-phase tree (R8 lesson: contended atomics are the enemy).

template<int D>
__global__ __launch_bounds__(256) void k_bnpart(const float4* __restrict__ X4,
                                                float* __restrict__ partial) {
    constexpr int Q   = D / 4;
    constexpr int RPI = 256 / Q;
    int tq = threadIdx.x % Q;
    int rg = threadIdx.x / Q;
    int chunk = (NN + BNBLK - 1) / BNBLK;
    int r0 = blockIdx.x * chunk;
    int r1 = r0 + chunk; if (r1 > NN) r1 = NN;
    float4 s  = {0.f, 0.f, 0.f, 0.f};
    float4 s2 = {0.f, 0.f, 0.f, 0.f};
    for (int r = r0 + rg; r < r1; r += RPI) {
        float4 v = X4[(size_t)r * Q + tq];
        s.x += v.x; s.y += v.y; s.z += v.z; s.w += v.w;
        s2.x += v.x * v.x; s2.y += v.y * v.y; s2.z += v.z * v.z; s2.w += v.w * v.w;
    }
    __shared__ float4 ls[256], ls2[256];
    ls[threadIdx.x] = s; ls2[threadIdx.x] = s2;
    __syncthreads();
    if (threadIdx.x < Q) {
        float4 a = ls[threadIdx.x], b = ls2[threadIdx.x];
        #pragma unroll
        for (int g = 1; g < RPI; g++) {
            float4 u = ls[g * Q + threadIdx.x], w = ls2[g * Q + threadIdx.x];
            a.x += u.x; a.y += u.y; a.z += u.z; a.w += u.w;
            b.x += w.x; b.y += w.y; b.z += w.z; b.w += w.w;
        }
        *(float4*)&partial[(size_t)blockIdx.x * 2 * D + threadIdx.x * 4]     = a;
        *(float4*)&partial[(size_t)blockIdx.x * 2 * D + D + threadIdx.x * 4] = b;
    }
}

// parallel final reduce: 1024 threads, G=1024/D groups strided over partials
template<int D>
__global__ __launch_bounds__(1024) void k_bnfin2(const float* __restrict__ partial,
                                                 const float* __restrict__ g,
                                                 const float* __restrict__ be,
                                                 float* __restrict__ AB) {
    constexpr int G = 1024 / D;
    int f  = threadIdx.x % D;
    int gr = threadIdx.x / D;
    float sum = 0.f, sq = 0.f;
    for (int b = gr; b < BNBLK; b += G) {
        sum += partial[(size_t)b * 2 * D + f];
        sq  += partial[(size_t)b * 2 * D + D + f];
    }
    __shared__ float ls[1024], ls2[1024];
    ls[threadIdx.x] = sum; ls2[threadIdx.x] = sq;
    __syncthreads();
    if (threadIdx.x < D) {
        float a = ls[threadIdx.x], b = ls2[threadIdx.x];
        for (int k = 1; k < G; k++) {
            a += ls[k * D + threadIdx.x];
            b += ls2[k * D + threadIdx.x];
        }
        float mu  = a / (float)NN;
        float var = b / (float)NN - mu * mu;
        var = fmaxf(var, 0.f);
        float inv = rsqrtf(var + EPSB);
        float sc = g[threadIdx.x] * inv;
        AB[threadIdx.x]     = sc;
        AB[D + threadIdx.x] = be[threadIdx.x] - mu * sc;
    }
}

__global__ void k_norm16(const float4* __restrict__ X, const float* __restrict__ AB,
                         uint2* __restrict__ Y, int d, int total4) {
    int t = blockIdx.x * blockDim.x + threadIdx.x;
    if (t >= total4) return;
    int f0 = (t * 4) & (d - 1);
    float4 v = X[t];
    float a0 = AB[f0],     a1 = AB[f0 + 1], a2 = AB[f0 + 2], a3 = AB[f0 + 3];
    float c0 = AB[d + f0], c1 = AB[d + f0 + 1], c2 = AB[d + f0 + 2], c3 = AB[d + f0 + 3];
    float o0 = fmaxf(v.x * a0 + c0, 0.f);
    float o1 = fmaxf(v.y * a1 + c1, 0.f);
    float o2 = fmaxf(v.z * a2 + c2, 0.f);
    float o3 = fmaxf(v.w * a3 + c3, 0.f);
    union { __half2 h; unsigned u; } p, q;
    p.h = __floats2half2_rn(o0, o1);
    q.h = __floats2half2_rn(o2, o3);
    Y[t] = make_uint2(p.u, q.u);
}

// ---------------------------------------------------------------- final edge MLP

__global__ __launch_bounds__(256) void k_edge16(const uint4* __restrict__ X,
                                                const int* __restrict__ src,
                                                const int* __restrict__ dst,
                                                const float* __restrict__ fcw,
                                                const float* __restrict__ fcb,
                                                float* __restrict__ out) {
    int lane = threadIdx.x & 3;
    size_t t = (size_t)blockIdx.x * 256 + threadIdx.x;
    int eid = (int)(t >> 2);
    if (eid >= EE) return;
    int s = src[eid], d = dst[eid];
    uint4 av = X[(size_t)s * 4 + lane];
    uint4 bv = X[(size_t)d * 4 + lane];
    const __half2* ap = (const __half2*)&av;
    const __half2* bp2 = (const __half2*)&bv;
    float v = 0.f;
    #pragma unroll
    for (int k = 0; k < 4; k++) {
        float2 fa = __half22float2(ap[k]);
        float2 fb = __half22float2(bp2[k]);
        float w0 = fcw[lane * 8 + 2 * k];
        float w1 = fcw[lane * 8 + 2 * k + 1];
        v += fa.x * fb.x * w0 + fa.y * fb.y * w1;
    }
    v += __shfl_xor(v, 1, 4);
    v += __shfl_xor(v, 2, 4);
    if (lane == 0) out[eid] = 1.f / (1.f + expf(-(v + fcb[0])));
}

// ---------------------------------------------------------------- launch

extern "C" void kernel_launch(void* const* d_in, const int* in_sizes, int n_in,
                              void* d_out, int out_size, void* d_ws, size_t ws_size,
                              hipStream_t stream) {
    const float* x0 = (const float*)d_in[0];
    const int* ei   = (const int*)d_in[1];
    const int* srcv = ei;
    const int* dstv = ei + EE;
    const float *W[5], *bp[5], *gp[5], *bep[5];
    int idx = 2;
    for (int l = 0; l < 5; l++) {
        W[l]   = (const float*)d_in[idx++];
        bp[l]  = (const float*)d_in[idx++];
        gp[l]  = (const float*)d_in[idx++];
        bep[l] = (const float*)d_in[idx++];
    }
    const float* fcw = (const float*)d_in[22];
    const float* fcb = (const float*)d_in[23];

    char* ws = (char*)d_ws;
    size_t off = 0;
    auto alloc = [&](size_t bytes) -> void* {
        void* p = ws + off;
        off = (off + bytes + 255) & ~(size_t)255;
        return p;
    };
    float*    bufA    = (float*)   alloc((size_t)NN * 256 * 4);
    __half*   act16   = (__half*)  alloc((size_t)NN * 256 * 2);
    __half*   x16     = (__half*)  alloc((size_t)NN * 128 * 2);
    __half*   Hh      = (__half*)  alloc((size_t)NN * 128 * 2);
    unsigned* barr    = (unsigned*)alloc((size_t)NB * BCAP * 4);
    int*      colv    = (int*)     alloc((size_t)EE * 4);
    int*      rowptr  = (int*)     alloc((size_t)NN * 4);
    int*      degcnt  = (int*)     alloc((size_t)NN * 4);
    float*    dis     = (float*)   alloc((size_t)NN * 4);
    int*      bcur    = (int*)     alloc((size_t)NB * 4);
    int*      scnblk  = (int*)     alloc(4096);
    float*    bnpart  = (float*)   alloc((size_t)BNBLK * 512 * 4);  // 1 MB
    float*    bnAB    = (float*)   alloc(512 * 4);
    __half*   Wp      = (__half*)  alloc((size_t)92160 * 2);
    const int woff[5] = {0, 16384, 49152, 81920, 90112};

    // ---- CSR build (binned counting sort)
    hipMemsetAsync(bcur, 0, (size_t)NB * 4, stream);
    k_bscat<<<(EE + 4095) / 4096, 256, 0, stream>>>(srcv, dstv, bcur, barr);
    k_bdeg<<<NB, 1024, 0, stream>>>(bcur, barr, degcnt, dis);
    int nScanBlk = (NN + 1023) / 1024;
    k_scan_block<<<nScanBlk, 1024, 0, stream>>>(degcnt, rowptr, scnblk, NN);
    k_scan_top<<<1, 64, 0, stream>>>(scnblk, nScanBlk);
    k_scan_add<<<nScanBlk, 1024, 0, stream>>>(rowptr, scnblk, NN);
    k_place<<<NB, 1024, 0, stream>>>(bcur, barr, rowptr, colv);

    // ---- casts / weight packs
    k_f2h<<<(NN * 128 / 4 + 255) / 256, 256, 0, stream>>>(
        (const float4*)x0, (uint2*)x16, NN * 128 / 4);
    k_wpack_all<<<(92160 + 255) / 256, 256, 0, stream>>>(W[0], W[1], W[2], W[3], W[4], Wp);

    int gx = (NN + 127) / 128;

    // ---- layer 0: mgemm(x16)->Hh ; agg(+b0)->bufA ; bn ; nscale->Hh
    {
        dim3 grid(gx, 128 / 64);
        k_mgemm<4, true, false><<<grid, 256, 0, stream>>>(x16, Wp + woff[0], Hh, NN, 128, 128, dis, nullptr, nullptr);
        k_agg_h<16, false><<<(NN + 15) / 16, 256, 0, stream>>>(
            (const uint4*)Hh, bufA, rowptr, degcnt, colv, dis, bp[0]);
        k_bnpart<128><<<BNBLK, 256, 0, stream>>>((const float4*)bufA, bnpart);
        k_bnfin2<128><<<1, 1024, 0, stream>>>(bnpart, gp[0], bep[0], bnAB);
        k_nscale<<<(NN * 16 + 255) / 256, 256, 0, stream>>>(bufA, bnAB, dis, (uint4*)Hh);
    }
    // ---- layer 1 (agg first): agg OUT16->act16 ; mgemm(act16,+b1)->bufA ; bn
    {
        k_agg_h<16, true><<<(NN + 15) / 16, 256, 0, stream>>>(
            (const uint4*)Hh, act16, rowptr, degcnt, colv, dis, nullptr);
        dim3 grid(gx, 256 / 64);
        k_mgemm<4, false, false><<<grid, 256, 0, stream>>>(act16, Wp + woff[1], bufA, NN, 128, 256, nullptr, bp[1], nullptr);
        k_bnpart<256><<<BNBLK, 256, 0, stream>>>((const float4*)bufA, bnpart);
        k_bnfin2<256><<<1, 1024, 0, stream>>>(bnpart, gp[1], bep[1], bnAB);
    }
    // ---- layer 2: mgemm(ABN: bufA d=256)->Hh ; agg(+b2)->bufA ; bn
    {
        dim3 grid(gx, 128 / 64);
        k_mgemm<4, true, true><<<grid, 256, 0, stream>>>(bufA, Wp + woff[2], Hh, NN, 256, 128, dis, nullptr, bnAB);
        k_agg_h<16, false><<<(NN + 15) / 16, 256, 0, stream>>>(
            (const uint4*)Hh, bufA, rowptr, degcnt, colv, dis, bp[2]);
        k_bnpart<128><<<BNBLK, 256, 0, stream>>>((const float4*)bufA, bnpart);
        k_bnfin2<128><<<1, 1024, 0, stream>>>(bnpart, gp[2], bep[2], bnAB);
    }
    // ---- layer 3 (d=64): mgemm(ABN: bufA d=128)->Hh ; agg(+b3)->bufA ; bn
    {
        dim3 grid(gx, 64 / 64);
        k_mgemm<4, true, true><<<grid, 256, 0, stream>>>(bufA, Wp + woff[3], Hh, NN, 128, 64, dis, nullptr, bnAB);
        k_agg_h<8, false><<<(NN + 31) / 32, 256, 0, stream>>>(
            (const uint4*)Hh, bufA, rowptr, degcnt, colv, dis, bp[3]);
        k_bnpart<64><<<BNBLK, 256, 0, stream>>>((const float4*)bufA, bnpart);
        k_bnfin2<64><<<1, 1024, 0, stream>>>(bnpart, gp[3], bep[3], bnAB);
    }
    // ---- layer 4 (d=32): mgemm(ABN: bufA d=64)->Hh ; agg(+b4)->bufA ; bn ; norm16
    {
        dim3 grid(gx, 1);
        k_mgemm<2, true, true><<<grid, 256, 0, stream>>>(bufA, Wp + woff[4], Hh, NN, 64, 32, dis, nullptr, bnAB);
        k_agg_h<4, false><<<(NN + 63) / 64, 256, 0, stream>>>(
            (const uint4*)Hh, bufA, rowptr, degcnt, colv, dis, bp[4]);
        k_bnpart<32><<<BNBLK, 256, 0, stream>>>((const float4*)bufA, bnpart);
        k_bnfin2<32><<<1, 1024, 0, stream>>>(bnpart, gp[4], bep[4], bnAB);
        int total4 = NN * 32 / 4;
        k_norm16<<<(total4 + 255) / 256, 256, 0, stream>>>(
            (const float4*)bufA, bnAB, (uint2*)act16, 32, total4);
    }

    size_t edgeThreads = (size_t)EE * 4;
    k_edge16<<<(unsigned)((edgeThreads + 255) / 256), 256, 0, stream>>>(
        (const uint4*)act16, srcv, dstv, fcw, fcb, (float*)d_out);
}